// Round 1
// baseline (238.715 us; speedup 1.0000x reference)
//
#include <hip/hip_runtime.h>
#include <hip/hip_bf16.h>
#include <math.h>

// AdAct piecewise-linear activation.
// R1 83us @ 2.4TB/s was latency-bound -> UNROLL=8 MLP + recip-mult bin select
// + nontemporal stores got structure right, but R4 rocprof showed 2.5 TB/s,
// VALUBusy 22%, Occupancy 56%: each of 4096 blocks paid a ~2k-cycle table
// build (global ns/a loads + 2 barriers + 4 divides/thread) for ONE 32KB
// streaming chunk -> >50% setup duty cycle.
// R5: split into two stream-ordered kernels.
//  - build_table (4 blocks): affine (A,B) table + scalar header -> d_ws.
//  - adact_main: setup = one coalesced 8KB table load -> LDS + 1 barrier;
//    grid = 2048 (exactly 8 blocks/CU resident, single residency round),
//    grid-stride 2 chunks/block. LDS 16KB -> 8KB.
// Affine transform unchanged: out = A[b] + B[b]*x, bin by x*(1/delta).

#define BLOCK 256
#define UNROLL 8

typedef float vfloat4 __attribute__((ext_vector_type(4)));

// ws layout: float hdr[8] = { r, s, rd, bits(bmin), a_first, a_last, -, - }
//            float2 tab[H] at ws+8 (32-byte offset, 16B-aligned)
__global__ void adact_build_table(const float* __restrict__ ns,
                                  const float* __restrict__ a,
                                  float* __restrict__ ws, int H)
{
    const int b = blockIdx.x * blockDim.x + threadIdx.x;
    const float r     = ns[0];
    const float s     = ns[H - 1];
    const float delta = ns[1] - ns[0];
    const float rd    = 1.0f / delta;
    const int   bmin  = (int)ceilf(r * rd) - 1;

    if (b == 0) {
        ws[0] = r; ws[1] = s; ws[2] = rd;
        ((int*)ws)[3] = bmin;
        ws[4] = a[0]; ws[5] = a[H - 1];
    }
    if (b < H) {
        // Replicate reference index math per bin exactly.
        int m1_raw = bmin + b;
        int m1 = m1_raw;
        if (m1 < 0) m1 = 0;
        if (m1 > H - 1) m1 = H - 1;
        int m2 = m1_raw + 1;
        if (m2 >= H) m2 = H - 1;
        if (m2 < 0)  m2 += H;
        if (m2 < 0)  m2 = 0;
        if (m2 > H - 1) m2 = H - 1;
        float ns1 = ns[m1], ns2 = ns[m2];
        float a1  = a[m1],  a2  = a[m2];
        float denom = ns2 - ns1;
        if (denom == 0.0f) denom = 1.0f;      // -> A=B=0, interp=0 (matches ref)
        float Bc = (a2 - a1) / denom;
        float Ac = (a1 * ns2 - a2 * ns1) / denom;
        ((float2*)(ws + 8))[b] = make_float2(Ac, Bc);
    }
}

__global__ __launch_bounds__(BLOCK) void adact_main(
    const float* __restrict__ x,
    const float* __restrict__ ws,
    float* __restrict__ out,
    int n, int H)
{
    extern __shared__ float smem[];
    float2* s_tab = (float2*)smem;             // H float2 (A,B) — 8KB at H=1024

    // Cheap setup: 8KB coalesced copy (L2-hot after block 0) + scalars.
    if ((H & 1) == 0) {
        const vfloat4* t4 = (const vfloat4*)(ws + 8);
        vfloat4* s4 = (vfloat4*)smem;
        for (int i = threadIdx.x; i < (H >> 1); i += BLOCK) s4[i] = t4[i];
    } else {
        const float2* t2 = (const float2*)(ws + 8);
        for (int i = threadIdx.x; i < H; i += BLOCK) s_tab[i] = t2[i];
    }
    const float r       = ws[0];
    const float s       = ws[1];
    const float rd      = ws[2];
    const int   bmin    = ((const int*)ws)[3];
    const float a_first = ws[4];
    const float a_last  = ws[5];
    __syncthreads();

    auto eval = [&](float xv) -> float {
        int b = (int)ceilf(xv * rd) - 1 - bmin;
        b = b < 0 ? 0 : (b > H - 1 ? H - 1 : b);
        float2 c = s_tab[b];
        float o = fmaf(c.y, xv, c.x);
        if (xv < r) o = a_first;
        if (xv > s) o = a_last;
        return o;
    };

    const int n4  = n >> 2;
    const int tid = threadIdx.x;
    const int chunk = BLOCK * UNROLL;          // float4s per block-chunk
    const vfloat4* __restrict__ x4 = (const vfloat4*)x;
    vfloat4* __restrict__ o4       = (vfloat4*)out;

    for (int base = blockIdx.x * chunk; base < n4; base += gridDim.x * chunk) {
        if (base + chunk <= n4) {
            // Full chunk: 8 independent loads in flight before any compute.
            vfloat4 v[UNROLL];
            #pragma unroll
            for (int k = 0; k < UNROLL; k++)
                v[k] = x4[base + k * BLOCK + tid];
            #pragma unroll
            for (int k = 0; k < UNROLL; k++) {
                vfloat4 ov;
                ov.x = eval(v[k].x);
                ov.y = eval(v[k].y);
                ov.z = eval(v[k].z);
                ov.w = eval(v[k].w);
                __builtin_nontemporal_store(ov, &o4[base + k * BLOCK + tid]);
            }
        } else {
            // Ragged last chunk.
            for (int i = base + tid; i < n4; i += BLOCK) {
                vfloat4 v = x4[i];
                vfloat4 ov;
                ov.x = eval(v.x);
                ov.y = eval(v.y);
                ov.z = eval(v.z);
                ov.w = eval(v.w);
                __builtin_nontemporal_store(ov, &o4[i]);
            }
        }
    }

    // Tail (n % 4 elements).
    const int rem  = n & 3;
    const int gtid = blockIdx.x * BLOCK + threadIdx.x;
    if (gtid < rem) {
        int i = (n4 << 2) + gtid;
        out[i] = eval(x[i]);
    }
}

// Fallback (ws too small): original single-kernel R3 path.
__global__ __launch_bounds__(BLOCK) void adact_fallback(
    const float* __restrict__ x,
    const float* __restrict__ ns,
    const float* __restrict__ a,
    float* __restrict__ out,
    int n, int H)
{
    extern __shared__ float smem[];
    float*  s_ns  = smem;
    float*  s_a   = smem + H;
    float2* s_tab = (float2*)(smem + 2 * H);

    for (int i = threadIdx.x; i < H; i += BLOCK) {
        s_ns[i] = ns[i];
        s_a[i]  = a[i];
    }
    __syncthreads();

    const float r       = s_ns[0];
    const float s       = s_ns[H - 1];
    const float delta   = s_ns[1] - s_ns[0];
    const float rd      = 1.0f / delta;
    const float a_first = s_a[0];
    const float a_last  = s_a[H - 1];
    const int bmin = (int)ceilf(r * rd) - 1;

    for (int b = threadIdx.x; b < H; b += BLOCK) {
        int m1_raw = bmin + b;
        int m1 = m1_raw;
        if (m1 < 0) m1 = 0;
        if (m1 > H - 1) m1 = H - 1;
        int m2 = m1_raw + 1;
        if (m2 >= H) m2 = H - 1;
        if (m2 < 0)  m2 += H;
        if (m2 < 0)  m2 = 0;
        if (m2 > H - 1) m2 = H - 1;
        float ns1 = s_ns[m1], ns2 = s_ns[m2];
        float a1  = s_a[m1],  a2  = s_a[m2];
        float denom = ns2 - ns1;
        if (denom == 0.0f) denom = 1.0f;
        float Bc = (a2 - a1) / denom;
        float Ac = (a1 * ns2 - a2 * ns1) / denom;
        s_tab[b] = make_float2(Ac, Bc);
    }
    __syncthreads();

    auto eval = [&](float xv) -> float {
        int b = (int)ceilf(xv * rd) - 1 - bmin;
        b = b < 0 ? 0 : (b > H - 1 ? H - 1 : b);
        float2 c = s_tab[b];
        float o = fmaf(c.y, xv, c.x);
        if (xv < r) o = a_first;
        if (xv > s) o = a_last;
        return o;
    };

    const int n4  = n >> 2;
    const int tid = threadIdx.x;
    const int chunk = BLOCK * UNROLL;
    const vfloat4* __restrict__ x4 = (const vfloat4*)x;
    vfloat4* __restrict__ o4       = (vfloat4*)out;

    for (int base = blockIdx.x * chunk; base < n4; base += gridDim.x * chunk) {
        if (base + chunk <= n4) {
            vfloat4 v[UNROLL];
            #pragma unroll
            for (int k = 0; k < UNROLL; k++)
                v[k] = x4[base + k * BLOCK + tid];
            #pragma unroll
            for (int k = 0; k < UNROLL; k++) {
                vfloat4 ov;
                ov.x = eval(v[k].x);
                ov.y = eval(v[k].y);
                ov.z = eval(v[k].z);
                ov.w = eval(v[k].w);
                __builtin_nontemporal_store(ov, &o4[base + k * BLOCK + tid]);
            }
        } else {
            for (int i = base + tid; i < n4; i += BLOCK) {
                vfloat4 v = x4[i];
                vfloat4 ov;
                ov.x = eval(v.x);
                ov.y = eval(v.y);
                ov.z = eval(v.z);
                ov.w = eval(v.w);
                __builtin_nontemporal_store(ov, &o4[i]);
            }
        }
    }

    const int rem  = n & 3;
    const int gtid = blockIdx.x * BLOCK + threadIdx.x;
    if (gtid < rem) {
        int i = (n4 << 2) + gtid;
        out[i] = eval(x[i]);
    }
}

extern "C" void kernel_launch(void* const* d_in, const int* in_sizes, int n_in,
                              void* d_out, int out_size, void* d_ws, size_t ws_size,
                              hipStream_t stream) {
    const float* x  = (const float*)d_in[0];
    const float* ns = (const float*)d_in[1];
    const float* a  = (const float*)d_in[2];
    float* out = (float*)d_out;
    const int n = in_sizes[0];
    const int H = in_sizes[1];

    const int chunk = BLOCK * UNROLL;
    int n4 = n >> 2;
    int nchunks = (n4 + chunk - 1) / chunk;
    if (nchunks < 1) nchunks = 1;

    const size_t ws_need = 32 + (size_t)H * 8;
    if (d_ws != nullptr && ws_size >= ws_need) {
        float* ws = (float*)d_ws;
        adact_build_table<<<(H + 255) / 256, 256, 0, stream>>>(ns, a, ws, H);
        // 2048 blocks = 8 blocks/CU x 256 CU: full wave residency in a single
        // round; at n=32M each block grid-strides exactly 2 chunks.
        int grid = nchunks < 2048 ? nchunks : 2048;
        adact_main<<<grid, BLOCK, (size_t)H * 8, stream>>>(x, ws, out, n, H);
    } else {
        int grid = nchunks;
        if (grid > 16384) grid = 16384;
        size_t shmem = (size_t)H * 16;
        adact_fallback<<<grid, BLOCK, shmem, stream>>>(x, ns, a, out, n, H);
    }
}

// Round 2
// 237.424 us; speedup vs baseline: 1.0054x; 1.0054x over previous
//
#include <hip/hip_runtime.h>
#include <hip/hip_bf16.h>
#include <math.h>

// AdAct piecewise-linear activation.
// History: R1 83us (latency-bound). R2/R3: UNROLL=8 MLP + recip-mult bin +
// NT stores -> 81us (no change). R5: hoisted table build to a tiny prologue
// kernel (VALUBusy 22->15%) -> 81us (no change). Counters: HBM 31%, VALU 15%,
// LDS-conflict ~5%, occupancy "55%" -- NOTHING saturated, while fillBuffer
// hits 6.6 TB/s and a plain float4 copy hits 6.3 TB/s on this chip.
// R6 theory: per-iteration exposed latency. vmcnt retires IN ISSUE ORDER on
// CDNA: the old loop issued chunk-i stores before chunk-i+1 loads, so every
// next-chunk load consume also waited for the previous chunk's NT stores to
// drain; plus next loads were only issued after all compute. Fix: software
// pipeline. Prefetch chunk i+1 (unconditional, clamped base) BEFORE
// compute+store of chunk i -> loads get a full iteration of slack and never
// wait behind stores. UNROLL 8->4 keeps cur[]+nxt[] under ~64 VGPR
// (8 waves/SIMD). Grid 2048, 4 chunks/block at n=32M (divides exactly).
// Affine transform unchanged: out = A[b] + B[b]*x, bin by x*(1/delta).

#define BLOCK 256
#define UNROLL 4

typedef float vfloat4 __attribute__((ext_vector_type(4)));

// ws layout: float hdr[8] = { r, s, rd, bits(bmin), a_first, a_last, -, - }
//            float2 tab[H] at ws+8 (32-byte offset, 16B-aligned)
__global__ void adact_build_table(const float* __restrict__ ns,
                                  const float* __restrict__ a,
                                  float* __restrict__ ws, int H)
{
    const int b = blockIdx.x * blockDim.x + threadIdx.x;
    const float r     = ns[0];
    const float s     = ns[H - 1];
    const float delta = ns[1] - ns[0];
    const float rd    = 1.0f / delta;
    const int   bmin  = (int)ceilf(r * rd) - 1;

    if (b == 0) {
        ws[0] = r; ws[1] = s; ws[2] = rd;
        ((int*)ws)[3] = bmin;
        ws[4] = a[0]; ws[5] = a[H - 1];
    }
    if (b < H) {
        // Replicate reference index math per bin exactly.
        int m1_raw = bmin + b;
        int m1 = m1_raw;
        if (m1 < 0) m1 = 0;
        if (m1 > H - 1) m1 = H - 1;
        int m2 = m1_raw + 1;
        if (m2 >= H) m2 = H - 1;
        if (m2 < 0)  m2 += H;
        if (m2 < 0)  m2 = 0;
        if (m2 > H - 1) m2 = H - 1;
        float ns1 = ns[m1], ns2 = ns[m2];
        float a1  = a[m1],  a2  = a[m2];
        float denom = ns2 - ns1;
        if (denom == 0.0f) denom = 1.0f;      // -> A=B=0, interp=0 (matches ref)
        float Bc = (a2 - a1) / denom;
        float Ac = (a1 * ns2 - a2 * ns1) / denom;
        ((float2*)(ws + 8))[b] = make_float2(Ac, Bc);
    }
}

__global__ __launch_bounds__(BLOCK) void adact_main(
    const float* __restrict__ x,
    const float* __restrict__ ws,
    float* __restrict__ out,
    int n, int H)
{
    extern __shared__ float smem[];
    float2* s_tab = (float2*)smem;             // H float2 (A,B) — 8KB at H=1024

    // Cheap setup: 8KB coalesced copy (L2-hot after block 0) + scalars.
    if ((H & 1) == 0) {
        const vfloat4* t4 = (const vfloat4*)(ws + 8);
        vfloat4* s4 = (vfloat4*)smem;
        for (int i = threadIdx.x; i < (H >> 1); i += BLOCK) s4[i] = t4[i];
    } else {
        const float2* t2 = (const float2*)(ws + 8);
        for (int i = threadIdx.x; i < H; i += BLOCK) s_tab[i] = t2[i];
    }
    const float r       = ws[0];
    const float s       = ws[1];
    const float rd      = ws[2];
    const int   bmin    = ((const int*)ws)[3];
    const float a_first = ws[4];
    const float a_last  = ws[5];
    __syncthreads();

    auto eval = [&](float xv) -> float {
        int b = (int)ceilf(xv * rd) - 1 - bmin;
        b = b < 0 ? 0 : (b > H - 1 ? H - 1 : b);
        float2 c = s_tab[b];
        float o = fmaf(c.y, xv, c.x);
        if (xv < r) o = a_first;
        if (xv > s) o = a_last;
        return o;
    };

    const int n4  = n >> 2;
    const int tid = threadIdx.x;
    const int chunk  = BLOCK * UNROLL;         // float4s per block-chunk
    const int stride = gridDim.x * chunk;
    const vfloat4* __restrict__ x4 = (const vfloat4*)x;
    vfloat4* __restrict__ o4       = (vfloat4*)out;

    int base  = blockIdx.x * chunk;
    bool have = (base + chunk <= n4);

    vfloat4 cur[UNROLL];
    if (have) {
        #pragma unroll
        for (int k = 0; k < UNROLL; k++)
            cur[k] = x4[base + k * BLOCK + tid];
    }

    while (have) {
        const int  nbase = base + stride;
        const bool hnext = (nbase + chunk <= n4);
        // Unconditional prefetch (clamped base) so the loads are issued
        // BEFORE any compute/stores of the current chunk. Loads-before-stores
        // issue order means the in-order vmcnt retire never makes a load
        // consume wait on the previous chunk's store drain.
        const int pbase = hnext ? nbase : base;
        vfloat4 nxt[UNROLL];
        #pragma unroll
        for (int k = 0; k < UNROLL; k++)
            nxt[k] = x4[pbase + k * BLOCK + tid];

        #pragma unroll
        for (int k = 0; k < UNROLL; k++) {
            vfloat4 v = cur[k];
            vfloat4 ov;
            ov.x = eval(v.x);
            ov.y = eval(v.y);
            ov.z = eval(v.z);
            ov.w = eval(v.w);
            __builtin_nontemporal_store(ov, &o4[base + k * BLOCK + tid]);
        }

        #pragma unroll
        for (int k = 0; k < UNROLL; k++) cur[k] = nxt[k];
        base = nbase;
        have = hnext;
    }

    // Ragged last chunk (base is this block's first uncovered chunk start).
    for (int i = base + tid; i < n4; i += BLOCK) {
        vfloat4 v = x4[i];
        vfloat4 ov;
        ov.x = eval(v.x);
        ov.y = eval(v.y);
        ov.z = eval(v.z);
        ov.w = eval(v.w);
        __builtin_nontemporal_store(ov, &o4[i]);
    }

    // Tail (n % 4 elements).
    const int rem  = n & 3;
    const int gtid = blockIdx.x * BLOCK + threadIdx.x;
    if (gtid < rem) {
        int i = (n4 << 2) + gtid;
        out[i] = eval(x[i]);
    }
}

// Fallback (ws too small): single-kernel path, same pipelined structure.
__global__ __launch_bounds__(BLOCK) void adact_fallback(
    const float* __restrict__ x,
    const float* __restrict__ ns,
    const float* __restrict__ a,
    float* __restrict__ out,
    int n, int H)
{
    extern __shared__ float smem[];
    float*  s_ns  = smem;
    float*  s_a   = smem + H;
    float2* s_tab = (float2*)(smem + 2 * H);

    for (int i = threadIdx.x; i < H; i += BLOCK) {
        s_ns[i] = ns[i];
        s_a[i]  = a[i];
    }
    __syncthreads();

    const float r       = s_ns[0];
    const float s       = s_ns[H - 1];
    const float delta   = s_ns[1] - s_ns[0];
    const float rd      = 1.0f / delta;
    const float a_first = s_a[0];
    const float a_last  = s_a[H - 1];
    const int bmin = (int)ceilf(r * rd) - 1;

    for (int b = threadIdx.x; b < H; b += BLOCK) {
        int m1_raw = bmin + b;
        int m1 = m1_raw;
        if (m1 < 0) m1 = 0;
        if (m1 > H - 1) m1 = H - 1;
        int m2 = m1_raw + 1;
        if (m2 >= H) m2 = H - 1;
        if (m2 < 0)  m2 += H;
        if (m2 < 0)  m2 = 0;
        if (m2 > H - 1) m2 = H - 1;
        float ns1 = s_ns[m1], ns2 = s_ns[m2];
        float a1  = s_a[m1],  a2  = s_a[m2];
        float denom = ns2 - ns1;
        if (denom == 0.0f) denom = 1.0f;
        float Bc = (a2 - a1) / denom;
        float Ac = (a1 * ns2 - a2 * ns1) / denom;
        s_tab[b] = make_float2(Ac, Bc);
    }
    __syncthreads();

    auto eval = [&](float xv) -> float {
        int b = (int)ceilf(xv * rd) - 1 - bmin;
        b = b < 0 ? 0 : (b > H - 1 ? H - 1 : b);
        float2 c = s_tab[b];
        float o = fmaf(c.y, xv, c.x);
        if (xv < r) o = a_first;
        if (xv > s) o = a_last;
        return o;
    };

    const int n4  = n >> 2;
    const int tid = threadIdx.x;
    const int chunk  = BLOCK * UNROLL;
    const int stride = gridDim.x * chunk;
    const vfloat4* __restrict__ x4 = (const vfloat4*)x;
    vfloat4* __restrict__ o4       = (vfloat4*)out;

    int base  = blockIdx.x * chunk;
    bool have = (base + chunk <= n4);

    vfloat4 cur[UNROLL];
    if (have) {
        #pragma unroll
        for (int k = 0; k < UNROLL; k++)
            cur[k] = x4[base + k * BLOCK + tid];
    }

    while (have) {
        const int  nbase = base + stride;
        const bool hnext = (nbase + chunk <= n4);
        const int  pbase = hnext ? nbase : base;
        vfloat4 nxt[UNROLL];
        #pragma unroll
        for (int k = 0; k < UNROLL; k++)
            nxt[k] = x4[pbase + k * BLOCK + tid];

        #pragma unroll
        for (int k = 0; k < UNROLL; k++) {
            vfloat4 v = cur[k];
            vfloat4 ov;
            ov.x = eval(v.x);
            ov.y = eval(v.y);
            ov.z = eval(v.z);
            ov.w = eval(v.w);
            __builtin_nontemporal_store(ov, &o4[base + k * BLOCK + tid]);
        }

        #pragma unroll
        for (int k = 0; k < UNROLL; k++) cur[k] = nxt[k];
        base = nbase;
        have = hnext;
    }

    for (int i = base + tid; i < n4; i += BLOCK) {
        vfloat4 v = x4[i];
        vfloat4 ov;
        ov.x = eval(v.x);
        ov.y = eval(v.y);
        ov.z = eval(v.z);
        ov.w = eval(v.w);
        __builtin_nontemporal_store(ov, &o4[i]);
    }

    const int rem  = n & 3;
    const int gtid = blockIdx.x * BLOCK + threadIdx.x;
    if (gtid < rem) {
        int i = (n4 << 2) + gtid;
        out[i] = eval(x[i]);
    }
}

extern "C" void kernel_launch(void* const* d_in, const int* in_sizes, int n_in,
                              void* d_out, int out_size, void* d_ws, size_t ws_size,
                              hipStream_t stream) {
    const float* x  = (const float*)d_in[0];
    const float* ns = (const float*)d_in[1];
    const float* a  = (const float*)d_in[2];
    float* out = (float*)d_out;
    const int n = in_sizes[0];
    const int H = in_sizes[1];

    const int chunk = BLOCK * UNROLL;
    int n4 = n >> 2;
    int nchunks = (n4 + chunk - 1) / chunk;
    if (nchunks < 1) nchunks = 1;

    const size_t ws_need = 32 + (size_t)H * 8;
    if (d_ws != nullptr && ws_size >= ws_need) {
        float* ws = (float*)d_ws;
        adact_build_table<<<(H + 255) / 256, 256, 0, stream>>>(ns, a, ws, H);
        // 2048 blocks = 8 blocks/CU x 256 CU; at n=32M each block pipelines
        // exactly 4 chunks (prefetch depth 1, no ragged path).
        int grid = nchunks < 2048 ? nchunks : 2048;
        adact_main<<<grid, BLOCK, (size_t)H * 8, stream>>>(x, ws, out, n, H);
    } else {
        int grid = nchunks < 2048 ? nchunks : 2048;
        size_t shmem = (size_t)H * 16;
        adact_fallback<<<grid, BLOCK, shmem, stream>>>(x, ns, a, out, n, H);
    }
}

// Round 4
// 236.921 us; speedup vs baseline: 1.0076x; 1.0021x over previous
//
#include <hip/hip_runtime.h>
#include <hip/hip_bf16.h>
#include <math.h>

// AdAct piecewise-linear activation.
// History: R1 83us naive. R2/R3 UNROLL-8 MLP + recip-mult + NT stores: 81us.
// R5 table-build hoisted to prologue kernel: 81us. R6 software pipeline:
// 81us. No pipe >25% busy -> remaining suspect is the per-element eval
// dependent chain. R7 tried sentinel table + fma-folded bin index: FAILED
// correctness (absmax 1.0). Root cause: fmaf(xv,rd,512) evaluates the bin
// argument at magnitude ~512 (ulp 6e-5), so tiny x>0 rounds back to 512.0
// and lands in bin -1 (denom==0 -> 0) instead of bin 0 (secant ~= -1): the
// reference is DISCONTINUOUS at x=0 with a jump of ~1.0. R8: keep the
// sentinel table (kills the 2cmp+2cndmask tail) but compute the bin as
// ceil(xv*rd) - bmin with an INTEGER subtract (exact, full relative
// precision at small |x|). Reinstate ONE guard (x>s -> a_last): the top
// sliver x in (6, 6.0059] would otherwise hit bin 1023 (o ~= x ~= 6, error
// ~5); bottom sliver errs only 5e-4 (wraparound secant passes through
// (-6, a0)) so sentinel-only is safe there.
// Eval: mul, ceil, cvt, isub, max, min, ds_read_b64, fma, cndmask.

#define BLOCK 256
#define UNROLL 4

typedef float vfloat4 __attribute__((ext_vector_type(4)));

// ws layout: float hdr[8] = { r, s, rd, bits(bmin), a_first, a_last, -, - }
//            float2 tab[H+2] at ws+8 (sentinel-padded affine table)
__global__ void adact_build_table(const float* __restrict__ ns,
                                  const float* __restrict__ a,
                                  float* __restrict__ ws, int H)
{
    const int b = blockIdx.x * blockDim.x + threadIdx.x;
    const float r     = ns[0];
    const float s     = ns[H - 1];
    const float delta = ns[1] - ns[0];
    const float rd    = 1.0f / delta;
    const int   bmin  = (int)ceilf(r * rd) - 1;

    float2* tab = (float2*)(ws + 8);

    if (b == 0) {
        ws[0] = r; ws[1] = s; ws[2] = rd;
        ((int*)ws)[3] = bmin;
        ws[4] = a[0]; ws[5] = a[H - 1];
        tab[0]     = make_float2(a[0],     0.0f);   // x*rd <= bmin+... -> a_first
        tab[H + 1] = make_float2(a[H - 1], 0.0f);   // x*rd > bmin+H+1 -> a_last
    }
    if (b < H) {
        // Replicate reference index math per bin exactly.
        int m1_raw = bmin + b;
        int m1 = m1_raw;
        if (m1 < 0) m1 = 0;
        if (m1 > H - 1) m1 = H - 1;
        int m2 = m1_raw + 1;
        if (m2 >= H) m2 = H - 1;
        if (m2 < 0)  m2 += H;
        if (m2 < 0)  m2 = 0;
        if (m2 > H - 1) m2 = H - 1;
        float ns1 = ns[m1], ns2 = ns[m2];
        float a1  = a[m1],  a2  = a[m2];
        float denom = ns2 - ns1;
        if (denom == 0.0f) denom = 1.0f;      // -> A=B=0, interp=0 (matches ref)
        float Bc = (a2 - a1) / denom;
        float Ac = (a1 * ns2 - a2 * ns1) / denom;
        tab[b + 1] = make_float2(Ac, Bc);
    }
}

__global__ __launch_bounds__(BLOCK) void adact_main(
    const float* __restrict__ x,
    const float* __restrict__ ws,
    float* __restrict__ out,
    int n, int H)
{
    extern __shared__ float smem[];
    float2* s_tab = (float2*)smem;             // (H+2) float2 (A,B)

    // Setup: coalesced table load (L2-hot after block 0) + scalars.
    const int tab_floats = (H + 2) * 2;
    if ((tab_floats & 3) == 0) {
        const vfloat4* t4 = (const vfloat4*)(ws + 8);
        vfloat4* s4 = (vfloat4*)smem;
        for (int i = threadIdx.x; i < (tab_floats >> 2); i += BLOCK) s4[i] = t4[i];
    } else {
        const float2* t2 = (const float2*)(ws + 8);
        for (int i = threadIdx.x; i < H + 2; i += BLOCK) s_tab[i] = t2[i];
    }
    const float s      = ws[1];
    const float rd     = ws[2];
    const int   bmin   = ((const int*)ws)[3];
    const float a_last = ws[5];
    const int   bhi    = H + 1;
    __syncthreads();

    auto eval = [&](float xv) -> float {
        // Integer-domain offset: ceil at native magnitude keeps full relative
        // precision near x=0 (the reference has a 1.0-jump there).
        int b = (int)ceilf(xv * rd) - bmin;
        b = b < 0 ? 0 : (b > bhi ? bhi : b);
        float2 c = s_tab[b];
        float o = fmaf(c.y, xv, c.x);
        return (xv > s) ? a_last : o;          // top sliver guard (see header)
    };

    const int n4  = n >> 2;
    const int tid = threadIdx.x;
    const int chunk  = BLOCK * UNROLL;         // float4s per block-chunk
    const int stride = gridDim.x * chunk;
    const vfloat4* __restrict__ x4 = (const vfloat4*)x;
    vfloat4* __restrict__ o4       = (vfloat4*)out;

    int base  = blockIdx.x * chunk;
    bool have = (base + chunk <= n4);

    vfloat4 cur[UNROLL];
    if (have) {
        #pragma unroll
        for (int k = 0; k < UNROLL; k++)
            cur[k] = x4[base + k * BLOCK + tid];
    }

    while (have) {
        const int  nbase = base + stride;
        const bool hnext = (nbase + chunk <= n4);
        const int  pbase = hnext ? nbase : base;
        vfloat4 nxt[UNROLL];
        #pragma unroll
        for (int k = 0; k < UNROLL; k++)
            nxt[k] = x4[pbase + k * BLOCK + tid];

        #pragma unroll
        for (int k = 0; k < UNROLL; k++) {
            vfloat4 v = cur[k];
            vfloat4 ov;
            ov.x = eval(v.x);
            ov.y = eval(v.y);
            ov.z = eval(v.z);
            ov.w = eval(v.w);
            __builtin_nontemporal_store(ov, &o4[base + k * BLOCK + tid]);
        }

        #pragma unroll
        for (int k = 0; k < UNROLL; k++) cur[k] = nxt[k];
        base = nbase;
        have = hnext;
    }

    // Ragged last chunk (base is this block's first uncovered chunk start).
    for (int i = base + tid; i < n4; i += BLOCK) {
        vfloat4 v = x4[i];
        vfloat4 ov;
        ov.x = eval(v.x);
        ov.y = eval(v.y);
        ov.z = eval(v.z);
        ov.w = eval(v.w);
        __builtin_nontemporal_store(ov, &o4[i]);
    }

    // Tail (n % 4 elements).
    const int rem  = n & 3;
    const int gtid = blockIdx.x * BLOCK + threadIdx.x;
    if (gtid < rem) {
        int i = (n4 << 2) + gtid;
        out[i] = eval(x[i]);
    }
}

// Fallback (ws too small): single-kernel path, builds sentinel table in LDS.
__global__ __launch_bounds__(BLOCK) void adact_fallback(
    const float* __restrict__ x,
    const float* __restrict__ ns,
    const float* __restrict__ a,
    float* __restrict__ out,
    int n, int H)
{
    extern __shared__ float smem[];
    float*  s_ns  = smem;                      // H floats
    float*  s_a   = smem + H;                  // H floats
    float2* s_tab = (float2*)(smem + 2 * H);   // (H+2) float2

    for (int i = threadIdx.x; i < H; i += BLOCK) {
        s_ns[i] = ns[i];
        s_a[i]  = a[i];
    }
    __syncthreads();

    const float r      = s_ns[0];
    const float s      = s_ns[H - 1];
    const float delta  = s_ns[1] - s_ns[0];
    const float rd     = 1.0f / delta;
    const float a_last = s_a[H - 1];
    const int   bmin   = (int)ceilf(r * rd) - 1;
    const int   bhi    = H + 1;

    if (threadIdx.x == 0) {
        s_tab[0]     = make_float2(s_a[0],     0.0f);
        s_tab[H + 1] = make_float2(s_a[H - 1], 0.0f);
    }
    for (int b = threadIdx.x; b < H; b += BLOCK) {
        int m1_raw = bmin + b;
        int m1 = m1_raw;
        if (m1 < 0) m1 = 0;
        if (m1 > H - 1) m1 = H - 1;
        int m2 = m1_raw + 1;
        if (m2 >= H) m2 = H - 1;
        if (m2 < 0)  m2 += H;
        if (m2 < 0)  m2 = 0;
        if (m2 > H - 1) m2 = H - 1;
        float ns1 = s_ns[m1], ns2 = s_ns[m2];
        float a1  = s_a[m1],  a2  = s_a[m2];
        float denom = ns2 - ns1;
        if (denom == 0.0f) denom = 1.0f;
        float Bc = (a2 - a1) / denom;
        float Ac = (a1 * ns2 - a2 * ns1) / denom;
        s_tab[b + 1] = make_float2(Ac, Bc);
    }
    __syncthreads();

    auto eval = [&](float xv) -> float {
        int b = (int)ceilf(xv * rd) - bmin;
        b = b < 0 ? 0 : (b > bhi ? bhi : b);
        float2 c = s_tab[b];
        float o = fmaf(c.y, xv, c.x);
        return (xv > s) ? a_last : o;
    };

    const int n4  = n >> 2;
    const int tid = threadIdx.x;
    const int chunk  = BLOCK * UNROLL;
    const int stride = gridDim.x * chunk;
    const vfloat4* __restrict__ x4 = (const vfloat4*)x;
    vfloat4* __restrict__ o4       = (vfloat4*)out;

    int base  = blockIdx.x * chunk;
    bool have = (base + chunk <= n4);

    vfloat4 cur[UNROLL];
    if (have) {
        #pragma unroll
        for (int k = 0; k < UNROLL; k++)
            cur[k] = x4[base + k * BLOCK + tid];
    }

    while (have) {
        const int  nbase = base + stride;
        const bool hnext = (nbase + chunk <= n4);
        const int  pbase = hnext ? nbase : base;
        vfloat4 nxt[UNROLL];
        #pragma unroll
        for (int k = 0; k < UNROLL; k++)
            nxt[k] = x4[pbase + k * BLOCK + tid];

        #pragma unroll
        for (int k = 0; k < UNROLL; k++) {
            vfloat4 v = cur[k];
            vfloat4 ov;
            ov.x = eval(v.x);
            ov.y = eval(v.y);
            ov.z = eval(v.z);
            ov.w = eval(v.w);
            __builtin_nontemporal_store(ov, &o4[base + k * BLOCK + tid]);
        }

        #pragma unroll
        for (int k = 0; k < UNROLL; k++) cur[k] = nxt[k];
        base = nbase;
        have = hnext;
    }

    for (int i = base + tid; i < n4; i += BLOCK) {
        vfloat4 v = x4[i];
        vfloat4 ov;
        ov.x = eval(v.x);
        ov.y = eval(v.y);
        ov.z = eval(v.z);
        ov.w = eval(v.w);
        __builtin_nontemporal_store(ov, &o4[i]);
    }

    const int rem  = n & 3;
    const int gtid = blockIdx.x * BLOCK + threadIdx.x;
    if (gtid < rem) {
        int i = (n4 << 2) + gtid;
        out[i] = eval(x[i]);
    }
}

extern "C" void kernel_launch(void* const* d_in, const int* in_sizes, int n_in,
                              void* d_out, int out_size, void* d_ws, size_t ws_size,
                              hipStream_t stream) {
    const float* x  = (const float*)d_in[0];
    const float* ns = (const float*)d_in[1];
    const float* a  = (const float*)d_in[2];
    float* out = (float*)d_out;
    const int n = in_sizes[0];
    const int H = in_sizes[1];

    const int chunk = BLOCK * UNROLL;
    int n4 = n >> 2;
    int nchunks = (n4 + chunk - 1) / chunk;
    if (nchunks < 1) nchunks = 1;

    const size_t ws_need = 32 + (size_t)(H + 2) * 8;
    if (d_ws != nullptr && ws_size >= ws_need) {
        float* ws = (float*)d_ws;
        adact_build_table<<<(H + 2 + 255) / 256, 256, 0, stream>>>(ns, a, ws, H);
        int grid = nchunks < 2048 ? nchunks : 2048;
        adact_main<<<grid, BLOCK, (size_t)(H + 2) * 8, stream>>>(x, ws, out, n, H);
    } else {
        int grid = nchunks < 2048 ? nchunks : 2048;
        size_t shmem = (size_t)(2 * H) * 4 + (size_t)(H + 2) * 8;
        adact_fallback<<<grid, BLOCK, shmem, stream>>>(x, ns, a, out, n, H);
    }
}